// Round 7
// baseline (220.446 us; speedup 1.0000x reference)
//
#include <hip/hip_runtime.h>

#define NF 128
#define NCHUNK 64          // edge chunks for histogram/counting passes
#define HIST_THREADS 512
#define NNW_MAX 25088      // max packed u16-pair words in LDS (100.3 KB); n_nodes <= 50176

typedef __attribute__((ext_vector_type(8))) short short8;   // 8 x bf16 (4 VGPRs)
typedef __attribute__((ext_vector_type(4))) float f32x4;
typedef unsigned int uint;
typedef unsigned short ushort;

// round-to-nearest-even f32 -> bf16
__device__ __forceinline__ ushort f2bf(float f) {
    uint u = __float_as_uint(f);
    uint r = (u + 0x7fffu + ((u >> 16) & 1u)) >> 16;
    return (ushort)r;
}
__device__ __forceinline__ float bflo(uint v) { return __uint_as_float(v << 16); }
__device__ __forceinline__ float bfhi(uint v) { return __uint_as_float(v & 0xffff0000u); }

// ---------------------------------------------------------------------------
// K1: LDS-privatized degree histograms — no global atomics.
// grid (NCHUNK, 2): y=0 counts dst, y=1 counts src. Packed 2 x u16 per u32.
// ---------------------------------------------------------------------------
__global__ __launch_bounds__(HIST_THREADS) void hist_kernel(const int* __restrict__ src,
                                                            const int* __restrict__ dst,
                                                            uint* __restrict__ partial_in,
                                                            uint* __restrict__ partial_out,
                                                            int n_edges, int nwords, int epb) {
    __shared__ uint h[NNW_MAX];
    for (int w = threadIdx.x; w < nwords; w += HIST_THREADS) h[w] = 0;
    __syncthreads();
    const int* idx = blockIdx.y ? src : dst;
    int ebeg = blockIdx.x * epb;
    int eend = min(ebeg + epb, n_edges);
    for (int e = ebeg + (int)threadIdx.x; e < eend; e += HIST_THREADS) {
        int node = idx[e];
        atomicAdd(&h[node >> 1], 1u << ((node & 1) * 16));
    }
    __syncthreads();
    uint* p = (blockIdx.y ? partial_out : partial_in) + (size_t)blockIdx.x * nwords;
    for (int w = threadIdx.x; w < nwords; w += HIST_THREADS) p[w] = h[w];
}

// ---------------------------------------------------------------------------
// K2 (fused): one pass over partials -> deg_in[], norm[], AND rel[c][w]
// (exclusive per-node prefix of dst-counts over chunks, packed u16; written
// over partial_out which is dead after the src-degree sums are read).
// ---------------------------------------------------------------------------
__global__ __launch_bounds__(256) void degnormrel_kernel(const uint* __restrict__ partial_in,
                                                         uint* __restrict__ partial_out,
                                                         int* __restrict__ deg_in,
                                                         float* __restrict__ norm,
                                                         int nwords, int n) {
    int w = blockIdx.x * 256 + threadIdx.x;
    if (w >= nwords) return;
    uint si0 = 0, si1 = 0, so0 = 0, so1 = 0;
    for (int c = 0; c < NCHUNK; ++c) {
        uint vi = partial_in[(size_t)c * nwords + w];
        uint vo = partial_out[(size_t)c * nwords + w];
        partial_out[(size_t)c * nwords + w] = si0 | (si1 << 16);   // rel = excl prefix (dst)
        si0 += vi & 0xffffu; si1 += vi >> 16;
        so0 += vo & 0xffffu; so1 += vo >> 16;
    }
    int n0 = 2 * w, n1 = 2 * w + 1;
    {
        uint di = si0 < 1u ? 1u : si0, dv = so0 < 1u ? 1u : so0;
        deg_in[n0] = (int)si0;
        norm[n0] = 1.0f / sqrtf((float)di * (float)dv);
    }
    if (n1 < n) {
        uint di = si1 < 1u ? 1u : si1, dv = so1 < 1u ? 1u : so1;
        deg_in[n1] = (int)si1;
        norm[n1] = 1.0f / sqrtf((float)di * (float)dv);
    }
}

// ---------------------------------------------------------------------------
// Fallback (n_nodes too big for LDS histogram): atomic path
// ---------------------------------------------------------------------------
__global__ __launch_bounds__(256) void deg_kernel(const int* __restrict__ src,
                                                  const int* __restrict__ dst,
                                                  int* __restrict__ deg_out,
                                                  int* __restrict__ deg_in,
                                                  int n_edges) {
    int i = blockIdx.x * 256 + threadIdx.x;
    if (i < n_edges) {
        atomicAdd(&deg_out[src[i]], 1);
        atomicAdd(&deg_in[dst[i]], 1);
    }
}
__global__ __launch_bounds__(256) void norm_kernel(const int* __restrict__ deg_out,
                                                   const int* __restrict__ deg_in,
                                                   float* __restrict__ norm, int n) {
    int i = blockIdx.x * 256 + threadIdx.x;
    if (i < n) {
        int dov = deg_out[i]; if (dov < 1) dov = 1;
        int div_ = deg_in[i]; if (div_ < 1) div_ = 1;
        norm[i] = 1.0f / sqrtf((float)dov * (float)div_);
    }
}

// ---------------------------------------------------------------------------
// K3: featg[cg][node][u] = bf16(feat*norm) packed, COLUMN-SLICED layout:
// slice cg holds features [16cg, 16cg+16) for all nodes = 1.6 MB, sized to
// fit one XCD's 4MB L2. Thread idx maps to (cg,node,u) so writes coalesce.
// ---------------------------------------------------------------------------
__global__ __launch_bounds__(256) void featn_kernel(const float* __restrict__ feat,
                                                    const float* __restrict__ norm,
                                                    uint* __restrict__ featg,
                                                    int n_nodes, int total) {
    int idx = blockIdx.x * 256 + threadIdx.x;
    if (idx >= total) return;
    int slice = n_nodes * 8;
    int cg = idx / slice;
    int rem = idx - cg * slice;
    int node = rem >> 3;
    int u = rem & 7;
    float nv = norm[node];
    float2 v = ((const float2*)feat)[node * 64 + cg * 8 + u];
    featg[idx] = (uint)f2bf(v.x * nv) | ((uint)f2bf(v.y * nv) << 16);
}

// ---------------------------------------------------------------------------
// K4: W^T bf16 packed
// ---------------------------------------------------------------------------
__global__ __launch_bounds__(256) void wt_kernel(const float* __restrict__ W,
                                                 uint* __restrict__ wt) {
    int idx = blockIdx.x * 256 + threadIdx.x;
    if (idx >= NF * NF / 2) return;
    int nrow = idx >> 6;
    int k2 = idx & 63;
    float a = W[(2 * k2) * NF + nrow];
    float b = W[(2 * k2 + 1) * NF + nrow];
    wt[idx] = (uint)f2bf(a) | ((uint)f2bf(b) << 16);
}

// ---------------------------------------------------------------------------
// Three-phase parallel exclusive scan of deg_in -> start[] (+cursor fallback)
// ---------------------------------------------------------------------------
__global__ __launch_bounds__(1024) void scan_sum_kernel(const int* __restrict__ deg,
                                                        int* __restrict__ bsum, int n) {
    int i = blockIdx.x * 1024 + threadIdx.x;
    int v = (i < n) ? deg[i] : 0;
#pragma unroll
    for (int off = 32; off >= 1; off >>= 1) v += __shfl_down(v, off, 64);
    __shared__ int ws[16];
    int wv = threadIdx.x >> 6, lane = threadIdx.x & 63;
    if (lane == 0) ws[wv] = v;
    __syncthreads();
    if (threadIdx.x == 0) {
        int s = 0;
#pragma unroll
        for (int k = 0; k < 16; ++k) s += ws[k];
        bsum[blockIdx.x] = s;
    }
}

__global__ __launch_bounds__(1024) void scan_bsum_kernel(int* __restrict__ bsum, int nb) {
    __shared__ int s[1024];
    int v = (threadIdx.x < (unsigned)nb) ? bsum[threadIdx.x] : 0;
    s[threadIdx.x] = v;
    __syncthreads();
    for (int off = 1; off < 1024; off <<= 1) {
        int t = (threadIdx.x >= (unsigned)off) ? s[threadIdx.x - off] : 0;
        __syncthreads();
        s[threadIdx.x] += t;
        __syncthreads();
    }
    if (threadIdx.x < (unsigned)nb) bsum[threadIdx.x] = s[threadIdx.x] - v;
}

__global__ __launch_bounds__(1024) void scan_final_kernel(const int* __restrict__ deg,
                                                          const int* __restrict__ bsum,
                                                          int* __restrict__ start,
                                                          int* __restrict__ cursor, int n) {
    int i = blockIdx.x * 1024 + threadIdx.x;
    int v = (i < n) ? deg[i] : 0;
    int lane = threadIdx.x & 63, wv = threadIdx.x >> 6;
    int incl = v;
#pragma unroll
    for (int off = 1; off < 64; off <<= 1) {
        int t = __shfl_up(incl, off, 64);
        if (lane >= off) incl += t;
    }
    __shared__ int ws[16];
    __shared__ int wo[16];
    if (lane == 63) ws[wv] = incl;
    __syncthreads();
    if (threadIdx.x == 0) {
        int s = 0;
#pragma unroll
        for (int k = 0; k < 16; ++k) { wo[k] = s; s += ws[k]; }
    }
    __syncthreads();
    int excl = incl - v + wo[wv] + bsum[blockIdx.x];
    if (i < n) { start[i] = excl; cursor[i] = excl; }
}

// ---------------------------------------------------------------------------
// K5: counting-sort CSR fill — zero global atomics.
// ---------------------------------------------------------------------------
__global__ __launch_bounds__(HIST_THREADS) void fill2_kernel(const int* __restrict__ src,
                                                             const int* __restrict__ dst,
                                                             const uint* __restrict__ rel,
                                                             const int* __restrict__ start,
                                                             int* __restrict__ csr_src,
                                                             int n_edges, int nwords, int epb) {
    __shared__ uint cur[NNW_MAX];
    for (int w = threadIdx.x; w < nwords; w += HIST_THREADS) cur[w] = 0;
    __syncthreads();
    int c = blockIdx.x;
    const uint* relc = rel + (size_t)c * nwords;
    int ebeg = c * epb;
    int eend = min(ebeg + epb, n_edges);
    for (int e = ebeg + (int)threadIdx.x; e < eend; e += HIST_THREADS) {
        int d = dst[e];
        int sh = (d & 1) * 16;
        uint old = atomicAdd(&cur[d >> 1], 1u << sh);
        uint rank = (old >> sh) & 0xffffu;
        uint relv = (relc[d >> 1] >> sh) & 0xffffu;
        int pos = start[d] + (int)(relv + rank);
        csr_src[pos] = src[e];
    }
}

// fallback atomic fill
__global__ __launch_bounds__(256) void fill_kernel(const int* __restrict__ src,
                                                   const int* __restrict__ dst,
                                                   int* __restrict__ cursor,
                                                   int* __restrict__ csr_src,
                                                   int n_edges) {
    int e = blockIdx.x * 256 + threadIdx.x;
    if (e < n_edges) {
        int d = dst[e];
        int pos = atomicAdd(&cursor[d], 1);
        csr_src[pos] = src[e];
    }
}

// ---------------------------------------------------------------------------
// K6: XCD-sliced gather. cg = blockIdx%8 -> round-robin block->XCD dispatch
// pins feature slice cg (1.6MB) to one XCD's L2. Wave = 1 node x 1 cg;
// lanes = 8 edges x 8 u32; per-lane partials, 3 shfl_xor rounds, lanes 0-7
// store 32B into row-major rst (gemm layout unchanged).
// ---------------------------------------------------------------------------
__global__ __launch_bounds__(256) void gather2_kernel(const uint* __restrict__ featg,
                                                      const int* __restrict__ csr_src,
                                                      const int* __restrict__ start,
                                                      const int* __restrict__ deg,
                                                      uint* __restrict__ rst_h,
                                                      int n_nodes) {
    int cg    = blockIdx.x & 7;
    int chunk = blockIdx.x >> 3;
    int node  = chunk * 4 + (threadIdx.x >> 6);
    if (node >= n_nodes) return;
    int lane = threadIdx.x & 63;
    int eg = lane >> 3;      // edge subgroup 0..7
    int u  = lane & 7;       // u32 within 32B slice row
    int beg = start[node];
    int d   = deg[node];
    const uint* fg = featg + (size_t)cg * n_nodes * 8;
    float ax = 0.0f, ay = 0.0f;
    for (int i = eg; i < d; i += 8) {
        int s = csr_src[beg + i];
        uint v = fg[(size_t)s * 8 + u];
        ax += bflo(v); ay += bfhi(v);
    }
#pragma unroll
    for (int m = 8; m <= 32; m <<= 1) {
        ax += __shfl_xor(ax, m, 64);
        ay += __shfl_xor(ay, m, 64);
    }
    if (eg == 0)
        rst_h[(size_t)node * 64 + cg * 8 + u] = (uint)f2bf(ax) | ((uint)f2bf(ay) << 16);
}

// ---------------------------------------------------------------------------
// K7: out = relu(rst_h @ W + bias) via mfma_f32_16x16x32_bf16 (no LDS)
// ---------------------------------------------------------------------------
__global__ __launch_bounds__(256) void gemm_mfma_kernel(const ushort* __restrict__ rst_h,
                                                        const ushort* __restrict__ wt_h,
                                                        const float* __restrict__ bias,
                                                        float* __restrict__ out,
                                                        int n_nodes) {
    int wave = threadIdx.x >> 6;
    int lane = threadIdx.x & 63;
    int row0 = blockIdx.x * 64 + wave * 16;
    if (row0 >= n_nodes) return;
    int l16 = lane & 15, lq = lane >> 4;

    short8 a[4];
    const ushort* ap = rst_h + (size_t)(row0 + l16) * NF + lq * 8;
#pragma unroll
    for (int kt = 0; kt < 4; ++kt) a[kt] = *(const short8*)(ap + kt * 32);

#pragma unroll
    for (int nt = 0; nt < 8; ++nt) {
        f32x4 acc = {0.0f, 0.0f, 0.0f, 0.0f};
        const ushort* bp = wt_h + (size_t)(nt * 16 + l16) * NF + lq * 8;
#pragma unroll
        for (int kt = 0; kt < 4; ++kt) {
            short8 b = *(const short8*)(bp + kt * 32);
            acc = __builtin_amdgcn_mfma_f32_16x16x32_bf16(a[kt], b, acc, 0, 0, 0);
        }
        int col = nt * 16 + l16;
        float bv = bias[col];
#pragma unroll
        for (int r = 0; r < 4; ++r) {
            int orow = row0 + lq * 4 + r;
            if (orow < n_nodes) {
                float v = acc[r] + bv;
                out[(size_t)orow * NF + col] = v > 0.0f ? v : 0.0f;
            }
        }
    }
}

extern "C" void kernel_launch(void* const* d_in, const int* in_sizes, int n_in,
                              void* d_out, int out_size, void* d_ws, size_t ws_size,
                              hipStream_t stream) {
    const float* feat = (const float*)d_in[0];
    const float* W    = (const float*)d_in[1];
    const float* bias = (const float*)d_in[2];
    const int*   src  = (const int*)d_in[3];
    const int*   dst  = (const int*)d_in[4];

    int n_nodes = in_sizes[0] / NF;
    int n_edges = in_sizes[3];

    // ws: [rst_h n*64 u32 (aliases hist partials)][featg n*64 u32][deg_in n]
    //     [deg_out n][norm n f32][start n][cursor n][bsum 1024][wt 8192 u32][csr_src E]
    char* ws = (char*)d_ws;
    size_t row_u32 = (size_t)n_nodes * 64;
    uint*  rst_h   = (uint*)ws;
    uint*  featg   = rst_h + row_u32;
    int*   deg_in  = (int*)(featg + row_u32);
    int*   deg_out = deg_in + n_nodes;
    float* norm    = (float*)(deg_out + n_nodes);
    int*   start   = (int*)(norm + n_nodes);
    int*   cursor  = start + n_nodes;
    int*   bsum    = cursor + n_nodes;
    uint*  wt      = (uint*)(bsum + 1024);
    int*   csr_src = (int*)(wt + NF * NF / 2);

    int nwords = (n_nodes + 1) / 2;
    int epb = (n_edges + NCHUNK - 1) / NCHUNK;
    bool fast = (nwords <= NNW_MAX) && ((size_t)2 * NCHUNK * nwords <= row_u32 + 64)
                && (epb < 65536);

    uint* partial_in  = rst_h;                          // aliases rst region
    uint* partial_out = rst_h + (size_t)NCHUNK * nwords;

    if (fast) {
        hist_kernel<<<dim3(NCHUNK, 2), HIST_THREADS, 0, stream>>>(
            src, dst, partial_in, partial_out, n_edges, nwords, epb);
        degnormrel_kernel<<<(nwords + 255) / 256, 256, 0, stream>>>(
            partial_in, partial_out, deg_in, norm, nwords, n_nodes);
    } else {
        hipMemsetAsync(deg_in, 0, 2 * (size_t)n_nodes * sizeof(int), stream);
        deg_kernel<<<(n_edges + 255) / 256, 256, 0, stream>>>(src, dst, deg_out, deg_in, n_edges);
        norm_kernel<<<(n_nodes + 255) / 256, 256, 0, stream>>>(deg_out, deg_in, norm, n_nodes);
    }

    int total = n_nodes * 64;
    featn_kernel<<<(total + 255) / 256, 256, 0, stream>>>(feat, norm, featg, n_nodes, total);
    wt_kernel<<<(NF * NF / 2 + 255) / 256, 256, 0, stream>>>(W, wt);

    int nb = (n_nodes + 1023) / 1024;
    scan_sum_kernel<<<nb, 1024, 0, stream>>>(deg_in, bsum, n_nodes);
    scan_bsum_kernel<<<1, 1024, 0, stream>>>(bsum, nb);
    scan_final_kernel<<<nb, 1024, 0, stream>>>(deg_in, bsum, start, cursor, n_nodes);

    if (fast) {
        fill2_kernel<<<NCHUNK, HIST_THREADS, 0, stream>>>(src, dst, partial_out, start,
                                                          csr_src, n_edges, nwords, epb);
    } else {
        fill_kernel<<<(n_edges + 255) / 256, 256, 0, stream>>>(src, dst, cursor, csr_src, n_edges);
    }

    int gblocks = ((n_nodes + 3) / 4) * 8;
    gather2_kernel<<<gblocks, 256, 0, stream>>>(featg, csr_src, start, deg_in, rst_h, n_nodes);
    gemm_mfma_kernel<<<(n_nodes + 63) / 64, 256, 0, stream>>>((const ushort*)rst_h,
                                                              (const ushort*)wt, bias,
                                                              (float*)d_out, n_nodes);
}

// Round 8
// 140.729 us; speedup vs baseline: 1.5665x; 1.5665x over previous
//
#include <hip/hip_runtime.h>

#define NF 128
#define NCHUNK 64          // edge chunks for histogram/counting passes
#define HIST_THREADS 1024
#define NNW_MAX 25088      // max packed u16-pair words in LDS (100.3 KB); n_nodes <= 50176

typedef __attribute__((ext_vector_type(8))) short short8;   // 8 x bf16 (4 VGPRs)
typedef __attribute__((ext_vector_type(4))) float f32x4;
typedef unsigned int uint;
typedef unsigned short ushort;

// round-to-nearest-even f32 -> bf16
__device__ __forceinline__ ushort f2bf(float f) {
    uint u = __float_as_uint(f);
    uint r = (u + 0x7fffu + ((u >> 16) & 1u)) >> 16;
    return (ushort)r;
}
__device__ __forceinline__ float bflo(uint v) { return __uint_as_float(v << 16); }
__device__ __forceinline__ float bfhi(uint v) { return __uint_as_float(v & 0xffff0000u); }

// ---------------------------------------------------------------------------
// K1: LDS-privatized degree histograms — no global atomics.
// grid (NCHUNK, 2): y=0 counts dst, y=1 counts src. Packed 2 x u16 per u32.
// ---------------------------------------------------------------------------
__global__ __launch_bounds__(HIST_THREADS) void hist_kernel(const int* __restrict__ src,
                                                            const int* __restrict__ dst,
                                                            uint* __restrict__ partial_in,
                                                            uint* __restrict__ partial_out,
                                                            int n_edges, int nwords, int epb) {
    __shared__ uint h[NNW_MAX];
    for (int w = threadIdx.x; w < nwords; w += HIST_THREADS) h[w] = 0;
    __syncthreads();
    const int* idx = blockIdx.y ? src : dst;
    int ebeg = blockIdx.x * epb;
    int eend = min(ebeg + epb, n_edges);
    for (int e = ebeg + (int)threadIdx.x; e < eend; e += HIST_THREADS) {
        int node = idx[e];
        atomicAdd(&h[node >> 1], 1u << ((node & 1) * 16));
    }
    __syncthreads();
    uint* p = (blockIdx.y ? partial_out : partial_in) + (size_t)blockIdx.x * nwords;
    for (int w = threadIdx.x; w < nwords; w += HIST_THREADS) p[w] = h[w];
}

// ---------------------------------------------------------------------------
// K2 (fused): one pass over partials -> deg_in[], norm[], AND rel[c][w]
// (exclusive per-node prefix of dst-counts over chunks, packed u16; written
// over partial_out which is dead after the src-degree sums are read).
// ---------------------------------------------------------------------------
__global__ __launch_bounds__(256) void degnormrel_kernel(const uint* __restrict__ partial_in,
                                                         uint* __restrict__ partial_out,
                                                         int* __restrict__ deg_in,
                                                         float* __restrict__ norm,
                                                         int nwords, int n) {
    int w = blockIdx.x * 256 + threadIdx.x;
    if (w >= nwords) return;
    uint si0 = 0, si1 = 0, so0 = 0, so1 = 0;
    for (int c = 0; c < NCHUNK; ++c) {
        uint vi = partial_in[(size_t)c * nwords + w];
        uint vo = partial_out[(size_t)c * nwords + w];
        partial_out[(size_t)c * nwords + w] = si0 | (si1 << 16);   // rel = excl prefix (dst)
        si0 += vi & 0xffffu; si1 += vi >> 16;
        so0 += vo & 0xffffu; so1 += vo >> 16;
    }
    int n0 = 2 * w, n1 = 2 * w + 1;
    {
        uint di = si0 < 1u ? 1u : si0, dv = so0 < 1u ? 1u : so0;
        deg_in[n0] = (int)si0;
        norm[n0] = 1.0f / sqrtf((float)di * (float)dv);
    }
    if (n1 < n) {
        uint di = si1 < 1u ? 1u : si1, dv = so1 < 1u ? 1u : so1;
        deg_in[n1] = (int)si1;
        norm[n1] = 1.0f / sqrtf((float)di * (float)dv);
    }
}

// ---------------------------------------------------------------------------
// Fallback (n_nodes too big for LDS histogram): atomic path
// ---------------------------------------------------------------------------
__global__ __launch_bounds__(256) void deg_kernel(const int* __restrict__ src,
                                                  const int* __restrict__ dst,
                                                  int* __restrict__ deg_out,
                                                  int* __restrict__ deg_in,
                                                  int n_edges) {
    int i = blockIdx.x * 256 + threadIdx.x;
    if (i < n_edges) {
        atomicAdd(&deg_out[src[i]], 1);
        atomicAdd(&deg_in[dst[i]], 1);
    }
}
__global__ __launch_bounds__(256) void norm_kernel(const int* __restrict__ deg_out,
                                                   const int* __restrict__ deg_in,
                                                   float* __restrict__ norm, int n) {
    int i = blockIdx.x * 256 + threadIdx.x;
    if (i < n) {
        int dov = deg_out[i]; if (dov < 1) dov = 1;
        int div_ = deg_in[i]; if (div_ < 1) div_ = 1;
        norm[i] = 1.0f / sqrtf((float)dov * (float)div_);
    }
}

// ---------------------------------------------------------------------------
// K3: featn = bf16(feat * norm[node]), packed 2/u32, row-major [node][64]
// ---------------------------------------------------------------------------
__global__ __launch_bounds__(256) void featn_kernel(const float* __restrict__ feat,
                                                    const float* __restrict__ norm,
                                                    uint* __restrict__ featn, int total) {
    int idx = blockIdx.x * 256 + threadIdx.x;
    if (idx >= total) return;
    int node = idx >> 6;
    float nv = norm[node];
    float2 v = ((const float2*)feat)[idx];
    featn[idx] = (uint)f2bf(v.x * nv) | ((uint)f2bf(v.y * nv) << 16);
}

// ---------------------------------------------------------------------------
// K4: W^T bf16 packed
// ---------------------------------------------------------------------------
__global__ __launch_bounds__(256) void wt_kernel(const float* __restrict__ W,
                                                 uint* __restrict__ wt) {
    int idx = blockIdx.x * 256 + threadIdx.x;
    if (idx >= NF * NF / 2) return;
    int nrow = idx >> 6;
    int k2 = idx & 63;
    float a = W[(2 * k2) * NF + nrow];
    float b = W[(2 * k2 + 1) * NF + nrow];
    wt[idx] = (uint)f2bf(a) | ((uint)f2bf(b) << 16);
}

// ---------------------------------------------------------------------------
// Three-phase parallel exclusive scan of deg_in -> start[] (+cursor fallback)
// ---------------------------------------------------------------------------
__global__ __launch_bounds__(1024) void scan_sum_kernel(const int* __restrict__ deg,
                                                        int* __restrict__ bsum, int n) {
    int i = blockIdx.x * 1024 + threadIdx.x;
    int v = (i < n) ? deg[i] : 0;
#pragma unroll
    for (int off = 32; off >= 1; off >>= 1) v += __shfl_down(v, off, 64);
    __shared__ int ws[16];
    int wv = threadIdx.x >> 6, lane = threadIdx.x & 63;
    if (lane == 0) ws[wv] = v;
    __syncthreads();
    if (threadIdx.x == 0) {
        int s = 0;
#pragma unroll
        for (int k = 0; k < 16; ++k) s += ws[k];
        bsum[blockIdx.x] = s;
    }
}

__global__ __launch_bounds__(1024) void scan_bsum_kernel(int* __restrict__ bsum, int nb) {
    __shared__ int s[1024];
    int v = (threadIdx.x < (unsigned)nb) ? bsum[threadIdx.x] : 0;
    s[threadIdx.x] = v;
    __syncthreads();
    for (int off = 1; off < 1024; off <<= 1) {
        int t = (threadIdx.x >= (unsigned)off) ? s[threadIdx.x - off] : 0;
        __syncthreads();
        s[threadIdx.x] += t;
        __syncthreads();
    }
    if (threadIdx.x < (unsigned)nb) bsum[threadIdx.x] = s[threadIdx.x] - v;
}

__global__ __launch_bounds__(1024) void scan_final_kernel(const int* __restrict__ deg,
                                                          const int* __restrict__ bsum,
                                                          int* __restrict__ start,
                                                          int* __restrict__ cursor, int n) {
    int i = blockIdx.x * 1024 + threadIdx.x;
    int v = (i < n) ? deg[i] : 0;
    int lane = threadIdx.x & 63, wv = threadIdx.x >> 6;
    int incl = v;
#pragma unroll
    for (int off = 1; off < 64; off <<= 1) {
        int t = __shfl_up(incl, off, 64);
        if (lane >= off) incl += t;
    }
    __shared__ int ws[16];
    __shared__ int wo[16];
    if (lane == 63) ws[wv] = incl;
    __syncthreads();
    if (threadIdx.x == 0) {
        int s = 0;
#pragma unroll
        for (int k = 0; k < 16; ++k) { wo[k] = s; s += ws[k]; }
    }
    __syncthreads();
    int excl = incl - v + wo[wv] + bsum[blockIdx.x];
    if (i < n) { start[i] = excl; cursor[i] = excl; }
}

// ---------------------------------------------------------------------------
// K5: counting-sort CSR fill — zero global atomics.
// ---------------------------------------------------------------------------
__global__ __launch_bounds__(HIST_THREADS) void fill2_kernel(const int* __restrict__ src,
                                                             const int* __restrict__ dst,
                                                             const uint* __restrict__ rel,
                                                             const int* __restrict__ start,
                                                             int* __restrict__ csr_src,
                                                             int n_edges, int nwords, int epb) {
    __shared__ uint cur[NNW_MAX];
    for (int w = threadIdx.x; w < nwords; w += HIST_THREADS) cur[w] = 0;
    __syncthreads();
    int c = blockIdx.x;
    const uint* relc = rel + (size_t)c * nwords;
    int ebeg = c * epb;
    int eend = min(ebeg + epb, n_edges);
    for (int e = ebeg + (int)threadIdx.x; e < eend; e += HIST_THREADS) {
        int d = dst[e];
        int sh = (d & 1) * 16;
        uint old = atomicAdd(&cur[d >> 1], 1u << sh);
        uint rank = (old >> sh) & 0xffffu;
        uint relv = (relc[d >> 1] >> sh) & 0xffffu;
        int pos = start[d] + (int)(relv + rank);
        csr_src[pos] = src[e];
    }
}

// fallback atomic fill
__global__ __launch_bounds__(256) void fill_kernel(const int* __restrict__ src,
                                                   const int* __restrict__ dst,
                                                   int* __restrict__ cursor,
                                                   int* __restrict__ csr_src,
                                                   int n_edges) {
    int e = blockIdx.x * 256 + threadIdx.x;
    if (e < n_edges) {
        int d = dst[e];
        int pos = atomicAdd(&cursor[d], 1);
        csr_src[pos] = src[e];
    }
}

// ---------------------------------------------------------------------------
// K6: gather-aggregate (bf16), wave per node, UNROLL-8: 8 independent 256B
// row loads in flight per wave (2KB/wave) to cover L2/L3/HBM miss latency.
// 4 accumulator pairs shorten the add chains.
// ---------------------------------------------------------------------------
__global__ __launch_bounds__(256) void gather_kernel(const uint* __restrict__ featn,
                                                     const int* __restrict__ csr_src,
                                                     const int* __restrict__ start,
                                                     const int* __restrict__ deg,
                                                     uint* __restrict__ rst_h,
                                                     int n_nodes) {
    int wid  = (blockIdx.x * 256 + threadIdx.x) >> 6;
    int lane = threadIdx.x & 63;
    if (wid >= n_nodes) return;
    int beg = start[wid];
    int end = beg + deg[wid];
    float ax0 = 0.f, ay0 = 0.f, ax1 = 0.f, ay1 = 0.f;
    float ax2 = 0.f, ay2 = 0.f, ax3 = 0.f, ay3 = 0.f;
    int i = beg;
    for (; i + 7 < end; i += 8) {
        int s0 = csr_src[i];
        int s1 = csr_src[i + 1];
        int s2 = csr_src[i + 2];
        int s3 = csr_src[i + 3];
        int s4 = csr_src[i + 4];
        int s5 = csr_src[i + 5];
        int s6 = csr_src[i + 6];
        int s7 = csr_src[i + 7];
        uint v0 = featn[(size_t)s0 * 64 + lane];
        uint v1 = featn[(size_t)s1 * 64 + lane];
        uint v2 = featn[(size_t)s2 * 64 + lane];
        uint v3 = featn[(size_t)s3 * 64 + lane];
        uint v4 = featn[(size_t)s4 * 64 + lane];
        uint v5 = featn[(size_t)s5 * 64 + lane];
        uint v6 = featn[(size_t)s6 * 64 + lane];
        uint v7 = featn[(size_t)s7 * 64 + lane];
        ax0 += bflo(v0); ay0 += bfhi(v0);
        ax1 += bflo(v1); ay1 += bfhi(v1);
        ax2 += bflo(v2); ay2 += bfhi(v2);
        ax3 += bflo(v3); ay3 += bfhi(v3);
        ax0 += bflo(v4); ay0 += bfhi(v4);
        ax1 += bflo(v5); ay1 += bfhi(v5);
        ax2 += bflo(v6); ay2 += bfhi(v6);
        ax3 += bflo(v7); ay3 += bfhi(v7);
    }
    for (; i + 1 < end; i += 2) {
        int s0 = csr_src[i];
        int s1 = csr_src[i + 1];
        uint v0 = featn[(size_t)s0 * 64 + lane];
        uint v1 = featn[(size_t)s1 * 64 + lane];
        ax0 += bflo(v0); ay0 += bfhi(v0);
        ax1 += bflo(v1); ay1 += bfhi(v1);
    }
    if (i < end) {
        int s = csr_src[i];
        uint v = featn[(size_t)s * 64 + lane];
        ax0 += bflo(v); ay0 += bfhi(v);
    }
    float ax = (ax0 + ax1) + (ax2 + ax3);
    float ay = (ay0 + ay1) + (ay2 + ay3);
    rst_h[(size_t)wid * 64 + lane] = (uint)f2bf(ax) | ((uint)f2bf(ay) << 16);
}

// ---------------------------------------------------------------------------
// K7: out = relu(rst_h @ W + bias) via mfma_f32_16x16x32_bf16 (no LDS)
// ---------------------------------------------------------------------------
__global__ __launch_bounds__(256) void gemm_mfma_kernel(const ushort* __restrict__ rst_h,
                                                        const ushort* __restrict__ wt_h,
                                                        const float* __restrict__ bias,
                                                        float* __restrict__ out,
                                                        int n_nodes) {
    int wave = threadIdx.x >> 6;
    int lane = threadIdx.x & 63;
    int row0 = blockIdx.x * 64 + wave * 16;
    if (row0 >= n_nodes) return;
    int l16 = lane & 15, lq = lane >> 4;

    short8 a[4];
    const ushort* ap = rst_h + (size_t)(row0 + l16) * NF + lq * 8;
#pragma unroll
    for (int kt = 0; kt < 4; ++kt) a[kt] = *(const short8*)(ap + kt * 32);

#pragma unroll
    for (int nt = 0; nt < 8; ++nt) {
        f32x4 acc = {0.0f, 0.0f, 0.0f, 0.0f};
        const ushort* bp = wt_h + (size_t)(nt * 16 + l16) * NF + lq * 8;
#pragma unroll
        for (int kt = 0; kt < 4; ++kt) {
            short8 b = *(const short8*)(bp + kt * 32);
            acc = __builtin_amdgcn_mfma_f32_16x16x32_bf16(a[kt], b, acc, 0, 0, 0);
        }
        int col = nt * 16 + l16;
        float bv = bias[col];
#pragma unroll
        for (int r = 0; r < 4; ++r) {
            int orow = row0 + lq * 4 + r;
            if (orow < n_nodes) {
                float v = acc[r] + bv;
                out[(size_t)orow * NF + col] = v > 0.0f ? v : 0.0f;
            }
        }
    }
}

extern "C" void kernel_launch(void* const* d_in, const int* in_sizes, int n_in,
                              void* d_out, int out_size, void* d_ws, size_t ws_size,
                              hipStream_t stream) {
    const float* feat = (const float*)d_in[0];
    const float* W    = (const float*)d_in[1];
    const float* bias = (const float*)d_in[2];
    const int*   src  = (const int*)d_in[3];
    const int*   dst  = (const int*)d_in[4];

    int n_nodes = in_sizes[0] / NF;
    int n_edges = in_sizes[3];

    // ws: [rst_h n*64 u32 (aliases hist partials)][featn n*64 u32][deg_in n]
    //     [deg_out n][norm n f32][start n][cursor n][bsum 1024][wt 8192 u32][csr_src E]
    char* ws = (char*)d_ws;
    size_t row_u32 = (size_t)n_nodes * 64;
    uint*  rst_h   = (uint*)ws;
    uint*  featn   = rst_h + row_u32;
    int*   deg_in  = (int*)(featn + row_u32);
    int*   deg_out = deg_in + n_nodes;
    float* norm    = (float*)(deg_out + n_nodes);
    int*   start   = (int*)(norm + n_nodes);
    int*   cursor  = start + n_nodes;
    int*   bsum    = cursor + n_nodes;
    uint*  wt      = (uint*)(bsum + 1024);
    int*   csr_src = (int*)(wt + NF * NF / 2);

    int nwords = (n_nodes + 1) / 2;
    int epb = (n_edges + NCHUNK - 1) / NCHUNK;
    bool fast = (nwords <= NNW_MAX) && ((size_t)2 * NCHUNK * nwords <= row_u32 + 64)
                && (epb < 65536);

    uint* partial_in  = rst_h;                          // aliases rst region
    uint* partial_out = rst_h + (size_t)NCHUNK * nwords;

    if (fast) {
        hist_kernel<<<dim3(NCHUNK, 2), HIST_THREADS, 0, stream>>>(
            src, dst, partial_in, partial_out, n_edges, nwords, epb);
        degnormrel_kernel<<<(nwords + 255) / 256, 256, 0, stream>>>(
            partial_in, partial_out, deg_in, norm, nwords, n_nodes);
    } else {
        hipMemsetAsync(deg_in, 0, 2 * (size_t)n_nodes * sizeof(int), stream);
        deg_kernel<<<(n_edges + 255) / 256, 256, 0, stream>>>(src, dst, deg_out, deg_in, n_edges);
        norm_kernel<<<(n_nodes + 255) / 256, 256, 0, stream>>>(deg_out, deg_in, norm, n_nodes);
    }

    int total = n_nodes * 64;
    featn_kernel<<<(total + 255) / 256, 256, 0, stream>>>(feat, norm, featn, total);
    wt_kernel<<<(NF * NF / 2 + 255) / 256, 256, 0, stream>>>(W, wt);

    int nb = (n_nodes + 1023) / 1024;
    scan_sum_kernel<<<nb, 1024, 0, stream>>>(deg_in, bsum, n_nodes);
    scan_bsum_kernel<<<1, 1024, 0, stream>>>(bsum, nb);
    scan_final_kernel<<<nb, 1024, 0, stream>>>(deg_in, bsum, start, cursor, n_nodes);

    if (fast) {
        fill2_kernel<<<NCHUNK, HIST_THREADS, 0, stream>>>(src, dst, partial_out, start,
                                                          csr_src, n_edges, nwords, epb);
    } else {
        fill_kernel<<<(n_edges + 255) / 256, 256, 0, stream>>>(src, dst, cursor, csr_src, n_edges);
    }

    gather_kernel<<<(n_nodes * 64 + 255) / 256, 256, 0, stream>>>(featn, csr_src, start,
                                                                  deg_in, rst_h, n_nodes);
    gemm_mfma_kernel<<<(n_nodes + 63) / 64, 256, 0, stream>>>((const ushort*)rst_h,
                                                              (const ushort*)wt, bias,
                                                              (float*)d_out, n_nodes);
}

// Round 9
// 121.422 us; speedup vs baseline: 1.8155x; 1.1590x over previous
//
#include <hip/hip_runtime.h>

#define NF 128
#define NCHUNK 64          // edge chunks
#define NRH 4              // hist node-range splits (LDS 25KB)
#define NRF 8              // fill node-range splits (LDS 12.5KB, XCD-pinned via bid%8)
#define NNW_MAX 25088      // max packed u16-pair words; n_nodes <= 50176
#define RWH_MAX ((NNW_MAX + NRH - 1) / NRH)   // 6272 words
#define RWF_MAX ((NNW_MAX + NRF - 1) / NRF)   // 3136 words

typedef __attribute__((ext_vector_type(8))) short short8;   // 8 x bf16 (4 VGPRs)
typedef __attribute__((ext_vector_type(4))) float f32x4;
typedef unsigned int uint;
typedef unsigned short ushort;

// round-to-nearest-even f32 -> bf16
__device__ __forceinline__ ushort f2bf(float f) {
    uint u = __float_as_uint(f);
    uint r = (u + 0x7fffu + ((u >> 16) & 1u)) >> 16;
    return (ushort)r;
}
__device__ __forceinline__ float bflo(uint v) { return __uint_as_float(v << 16); }
__device__ __forceinline__ float bfhi(uint v) { return __uint_as_float(v & 0xffff0000u); }

// ---------------------------------------------------------------------------
// K1: range-split LDS degree histograms — no global atomics, all CUs busy.
// grid (NCHUNK, 2, NRH): x=chunk, y: 0=dst 1=src, z=node range. Each block
// re-reads the chunk's 50KB index slice (L2-hit) but only counts nodes in its
// range (25KB LDS). Dumps its range slice of partial[c].
// ---------------------------------------------------------------------------
__global__ __launch_bounds__(512) void hist_kernel(const int* __restrict__ src,
                                                   const int* __restrict__ dst,
                                                   uint* __restrict__ partial_in,
                                                   uint* __restrict__ partial_out,
                                                   int n_edges, int nwords, int epb, int rw) {
    __shared__ uint h[RWH_MAX];
    int wbeg = blockIdx.z * rw;
    int wend = min(wbeg + rw, nwords);
    int nw = wend - wbeg;
    for (int w = threadIdx.x; w < nw; w += 512) h[w] = 0;
    __syncthreads();
    const int* idx = blockIdx.y ? src : dst;
    int ebeg = blockIdx.x * epb;
    int eend = min(ebeg + epb, n_edges);
    int nodelo = wbeg * 2, nodehi = wend * 2;
    for (int e = ebeg + (int)threadIdx.x; e < eend; e += 512) {
        int node = idx[e];
        if (node >= nodelo && node < nodehi)
            atomicAdd(&h[(node >> 1) - wbeg], 1u << ((node & 1) * 16));
    }
    __syncthreads();
    uint* p = (blockIdx.y ? partial_out : partial_in) + (size_t)blockIdx.x * nwords + wbeg;
    for (int w = threadIdx.x; w < nw; w += 512) p[w] = h[w];
}

// ---------------------------------------------------------------------------
// K2 (fused): one pass over partials -> deg_in[], norm[], AND rel[c][w]
// (exclusive per-node prefix of dst-counts over chunks, packed u16; written
// over partial_out which is dead after the src sums are read).
// ---------------------------------------------------------------------------
__global__ __launch_bounds__(256) void degnormrel_kernel(const uint* __restrict__ partial_in,
                                                         uint* __restrict__ partial_out,
                                                         int* __restrict__ deg_in,
                                                         float* __restrict__ norm,
                                                         int nwords, int n) {
    int w = blockIdx.x * 256 + threadIdx.x;
    if (w >= nwords) return;
    uint si0 = 0, si1 = 0, so0 = 0, so1 = 0;
    for (int c = 0; c < NCHUNK; ++c) {
        uint vi = partial_in[(size_t)c * nwords + w];
        uint vo = partial_out[(size_t)c * nwords + w];
        partial_out[(size_t)c * nwords + w] = si0 | (si1 << 16);   // rel = excl prefix (dst)
        si0 += vi & 0xffffu; si1 += vi >> 16;
        so0 += vo & 0xffffu; so1 += vo >> 16;
    }
    int n0 = 2 * w, n1 = 2 * w + 1;
    {
        uint di = si0 < 1u ? 1u : si0, dv = so0 < 1u ? 1u : so0;
        deg_in[n0] = (int)si0;
        norm[n0] = 1.0f / sqrtf((float)di * (float)dv);
    }
    if (n1 < n) {
        uint di = si1 < 1u ? 1u : si1, dv = so1 < 1u ? 1u : so1;
        deg_in[n1] = (int)si1;
        norm[n1] = 1.0f / sqrtf((float)di * (float)dv);
    }
}

// ---------------------------------------------------------------------------
// Fallback (n too big / ws too small): atomic path
// ---------------------------------------------------------------------------
__global__ __launch_bounds__(256) void deg_kernel(const int* __restrict__ src,
                                                  const int* __restrict__ dst,
                                                  int* __restrict__ deg_out,
                                                  int* __restrict__ deg_in,
                                                  int n_edges) {
    int i = blockIdx.x * 256 + threadIdx.x;
    if (i < n_edges) {
        atomicAdd(&deg_out[src[i]], 1);
        atomicAdd(&deg_in[dst[i]], 1);
    }
}
__global__ __launch_bounds__(256) void norm_kernel(const int* __restrict__ deg_out,
                                                   const int* __restrict__ deg_in,
                                                   float* __restrict__ norm, int n) {
    int i = blockIdx.x * 256 + threadIdx.x;
    if (i < n) {
        int dov = deg_out[i]; if (dov < 1) dov = 1;
        int div_ = deg_in[i]; if (div_ < 1) div_ = 1;
        norm[i] = 1.0f / sqrtf((float)dov * (float)div_);
    }
}

// ---------------------------------------------------------------------------
// K3: featn = bf16(feat * norm[node]), packed 2/u32, row-major [node][64]
// ---------------------------------------------------------------------------
__global__ __launch_bounds__(256) void featn_kernel(const float* __restrict__ feat,
                                                    const float* __restrict__ norm,
                                                    uint* __restrict__ featn, int total) {
    int idx = blockIdx.x * 256 + threadIdx.x;
    if (idx >= total) return;
    int node = idx >> 6;
    float nv = norm[node];
    float2 v = ((const float2*)feat)[idx];
    featn[idx] = (uint)f2bf(v.x * nv) | ((uint)f2bf(v.y * nv) << 16);
}

// ---------------------------------------------------------------------------
// K4: W^T bf16 packed
// ---------------------------------------------------------------------------
__global__ __launch_bounds__(256) void wt_kernel(const float* __restrict__ W,
                                                 uint* __restrict__ wt) {
    int idx = blockIdx.x * 256 + threadIdx.x;
    if (idx >= NF * NF / 2) return;
    int nrow = idx >> 6;
    int k2 = idx & 63;
    float a = W[(2 * k2) * NF + nrow];
    float b = W[(2 * k2 + 1) * NF + nrow];
    wt[idx] = (uint)f2bf(a) | ((uint)f2bf(b) << 16);
}

// ---------------------------------------------------------------------------
// Three-phase parallel exclusive scan of deg_in -> start[] (+cursor fallback)
// ---------------------------------------------------------------------------
__global__ __launch_bounds__(1024) void scan_sum_kernel(const int* __restrict__ deg,
                                                        int* __restrict__ bsum, int n) {
    int i = blockIdx.x * 1024 + threadIdx.x;
    int v = (i < n) ? deg[i] : 0;
#pragma unroll
    for (int off = 32; off >= 1; off >>= 1) v += __shfl_down(v, off, 64);
    __shared__ int ws[16];
    int wv = threadIdx.x >> 6, lane = threadIdx.x & 63;
    if (lane == 0) ws[wv] = v;
    __syncthreads();
    if (threadIdx.x == 0) {
        int s = 0;
#pragma unroll
        for (int k = 0; k < 16; ++k) s += ws[k];
        bsum[blockIdx.x] = s;
    }
}

__global__ __launch_bounds__(1024) void scan_bsum_kernel(int* __restrict__ bsum, int nb) {
    __shared__ int s[1024];
    int v = (threadIdx.x < (unsigned)nb) ? bsum[threadIdx.x] : 0;
    s[threadIdx.x] = v;
    __syncthreads();
    for (int off = 1; off < 1024; off <<= 1) {
        int t = (threadIdx.x >= (unsigned)off) ? s[threadIdx.x - off] : 0;
        __syncthreads();
        s[threadIdx.x] += t;
        __syncthreads();
    }
    if (threadIdx.x < (unsigned)nb) bsum[threadIdx.x] = s[threadIdx.x] - v;
}

__global__ __launch_bounds__(1024) void scan_final_kernel(const int* __restrict__ deg,
                                                          const int* __restrict__ bsum,
                                                          int* __restrict__ start,
                                                          int* __restrict__ cursor, int n) {
    int i = blockIdx.x * 1024 + threadIdx.x;
    int v = (i < n) ? deg[i] : 0;
    int lane = threadIdx.x & 63, wv = threadIdx.x >> 6;
    int incl = v;
#pragma unroll
    for (int off = 1; off < 64; off <<= 1) {
        int t = __shfl_up(incl, off, 64);
        if (lane >= off) incl += t;
    }
    __shared__ int ws[16];
    __shared__ int wo[16];
    if (lane == 63) ws[wv] = incl;
    __syncthreads();
    if (threadIdx.x == 0) {
        int s = 0;
#pragma unroll
        for (int k = 0; k < 16; ++k) { wo[k] = s; s += ws[k]; }
    }
    __syncthreads();
    int excl = incl - v + wo[wv] + bsum[blockIdx.x];
    if (i < n) { start[i] = excl; cursor[i] = excl; }
}

// ---------------------------------------------------------------------------
// K5: range-split counting-sort CSR fill — zero global atomics.
// bid = chunk*NRF + range, so bid%8 = range -> (heuristic) range r on XCD r:
// each csr slice is written from one XCD only => writes coalesce in its L2.
// ---------------------------------------------------------------------------
__global__ __launch_bounds__(512) void fill3_kernel(const int* __restrict__ src,
                                                    const int* __restrict__ dst,
                                                    const uint* __restrict__ rel,
                                                    const int* __restrict__ start,
                                                    int* __restrict__ csr_src,
                                                    int n_edges, int nwords, int epb, int rwf) {
    __shared__ uint cur[RWF_MAX];
    int c = blockIdx.x >> 3;          // NRF==8
    int r = blockIdx.x & 7;
    int wbeg = r * rwf;
    int wend = min(wbeg + rwf, nwords);
    int nw = wend - wbeg;
    for (int w = threadIdx.x; w < nw; w += 512) cur[w] = 0;
    __syncthreads();
    const uint* relc = rel + (size_t)c * nwords;
    int ebeg = c * epb;
    int eend = min(ebeg + epb, n_edges);
    int nodelo = wbeg * 2, nodehi = wend * 2;
    for (int e = ebeg + (int)threadIdx.x; e < eend; e += 512) {
        int d = dst[e];
        if (d >= nodelo && d < nodehi) {
            int sh = (d & 1) * 16;
            uint old = atomicAdd(&cur[(d >> 1) - wbeg], 1u << sh);
            uint rank = (old >> sh) & 0xffffu;
            uint relv = (relc[d >> 1] >> sh) & 0xffffu;
            int pos = start[d] + (int)(relv + rank);
            csr_src[pos] = src[e];
        }
    }
}

// fallback atomic fill
__global__ __launch_bounds__(256) void fill_kernel(const int* __restrict__ src,
                                                   const int* __restrict__ dst,
                                                   int* __restrict__ cursor,
                                                   int* __restrict__ csr_src,
                                                   int n_edges) {
    int e = blockIdx.x * 256 + threadIdx.x;
    if (e < n_edges) {
        int d = dst[e];
        int pos = atomicAdd(&cursor[d], 1);
        csr_src[pos] = src[e];
    }
}

// ---------------------------------------------------------------------------
// K6: gather-aggregate (bf16), wave per node, unroll-8 (8 independent 256B
// row loads in flight per wave; 4 accumulator pairs).
// ---------------------------------------------------------------------------
__global__ __launch_bounds__(256) void gather_kernel(const uint* __restrict__ featn,
                                                     const int* __restrict__ csr_src,
                                                     const int* __restrict__ start,
                                                     const int* __restrict__ deg,
                                                     uint* __restrict__ rst_h,
                                                     int n_nodes) {
    int wid  = (blockIdx.x * 256 + threadIdx.x) >> 6;
    int lane = threadIdx.x & 63;
    if (wid >= n_nodes) return;
    int beg = start[wid];
    int end = beg + deg[wid];
    float ax0 = 0.f, ay0 = 0.f, ax1 = 0.f, ay1 = 0.f;
    float ax2 = 0.f, ay2 = 0.f, ax3 = 0.f, ay3 = 0.f;
    int i = beg;
    for (; i + 7 < end; i += 8) {
        int s0 = csr_src[i];
        int s1 = csr_src[i + 1];
        int s2 = csr_src[i + 2];
        int s3 = csr_src[i + 3];
        int s4 = csr_src[i + 4];
        int s5 = csr_src[i + 5];
        int s6 = csr_src[i + 6];
        int s7 = csr_src[i + 7];
        uint v0 = featn[(size_t)s0 * 64 + lane];
        uint v1 = featn[(size_t)s1 * 64 + lane];
        uint v2 = featn[(size_t)s2 * 64 + lane];
        uint v3 = featn[(size_t)s3 * 64 + lane];
        uint v4 = featn[(size_t)s4 * 64 + lane];
        uint v5 = featn[(size_t)s5 * 64 + lane];
        uint v6 = featn[(size_t)s6 * 64 + lane];
        uint v7 = featn[(size_t)s7 * 64 + lane];
        ax0 += bflo(v0); ay0 += bfhi(v0);
        ax1 += bflo(v1); ay1 += bfhi(v1);
        ax2 += bflo(v2); ay2 += bfhi(v2);
        ax3 += bflo(v3); ay3 += bfhi(v3);
        ax0 += bflo(v4); ay0 += bfhi(v4);
        ax1 += bflo(v5); ay1 += bfhi(v5);
        ax2 += bflo(v6); ay2 += bfhi(v6);
        ax3 += bflo(v7); ay3 += bfhi(v7);
    }
    for (; i + 1 < end; i += 2) {
        int s0 = csr_src[i];
        int s1 = csr_src[i + 1];
        uint v0 = featn[(size_t)s0 * 64 + lane];
        uint v1 = featn[(size_t)s1 * 64 + lane];
        ax0 += bflo(v0); ay0 += bfhi(v0);
        ax1 += bflo(v1); ay1 += bfhi(v1);
    }
    if (i < end) {
        int s = csr_src[i];
        uint v = featn[(size_t)s * 64 + lane];
        ax0 += bflo(v); ay0 += bfhi(v);
    }
    float ax = (ax0 + ax1) + (ax2 + ax3);
    float ay = (ay0 + ay1) + (ay2 + ay3);
    rst_h[(size_t)wid * 64 + lane] = (uint)f2bf(ax) | ((uint)f2bf(ay) << 16);
}

// ---------------------------------------------------------------------------
// K7: out = relu(rst_h @ W + bias) via mfma_f32_16x16x32_bf16 (no LDS)
// ---------------------------------------------------------------------------
__global__ __launch_bounds__(256) void gemm_mfma_kernel(const ushort* __restrict__ rst_h,
                                                        const ushort* __restrict__ wt_h,
                                                        const float* __restrict__ bias,
                                                        float* __restrict__ out,
                                                        int n_nodes) {
    int wave = threadIdx.x >> 6;
    int lane = threadIdx.x & 63;
    int row0 = blockIdx.x * 64 + wave * 16;
    if (row0 >= n_nodes) return;
    int l16 = lane & 15, lq = lane >> 4;

    short8 a[4];
    const ushort* ap = rst_h + (size_t)(row0 + l16) * NF + lq * 8;
#pragma unroll
    for (int kt = 0; kt < 4; ++kt) a[kt] = *(const short8*)(ap + kt * 32);

#pragma unroll
    for (int nt = 0; nt < 8; ++nt) {
        f32x4 acc = {0.0f, 0.0f, 0.0f, 0.0f};
        const ushort* bp = wt_h + (size_t)(nt * 16 + l16) * NF + lq * 8;
#pragma unroll
        for (int kt = 0; kt < 4; ++kt) {
            short8 b = *(const short8*)(bp + kt * 32);
            acc = __builtin_amdgcn_mfma_f32_16x16x32_bf16(a[kt], b, acc, 0, 0, 0);
        }
        int col = nt * 16 + l16;
        float bv = bias[col];
#pragma unroll
        for (int r = 0; r < 4; ++r) {
            int orow = row0 + lq * 4 + r;
            if (orow < n_nodes) {
                float v = acc[r] + bv;
                out[(size_t)orow * NF + col] = v > 0.0f ? v : 0.0f;
            }
        }
    }
}

extern "C" void kernel_launch(void* const* d_in, const int* in_sizes, int n_in,
                              void* d_out, int out_size, void* d_ws, size_t ws_size,
                              hipStream_t stream) {
    const float* feat = (const float*)d_in[0];
    const float* W    = (const float*)d_in[1];
    const float* bias = (const float*)d_in[2];
    const int*   src  = (const int*)d_in[3];
    const int*   dst  = (const int*)d_in[4];

    int n_nodes = in_sizes[0] / NF;
    int n_edges = in_sizes[3];

    // ws: [rst_h n*64 u32][featn n*64 u32][deg_in n][deg_out n][norm n f32]
    //     [start n][cursor n][bsum 1024][wt 8192 u32][csr_src E][partials 2*NCHUNK*nwords u32]
    char* ws = (char*)d_ws;
    size_t row_u32 = (size_t)n_nodes * 64;
    uint*  rst_h   = (uint*)ws;
    uint*  featn   = rst_h + row_u32;
    int*   deg_in  = (int*)(featn + row_u32);
    int*   deg_out = deg_in + n_nodes;
    float* norm    = (float*)(deg_out + n_nodes);
    int*   start   = (int*)(norm + n_nodes);
    int*   cursor  = start + n_nodes;
    int*   bsum    = cursor + n_nodes;
    uint*  wt      = (uint*)(bsum + 1024);
    int*   csr_src = (int*)(wt + NF * NF / 2);
    uint*  partial_in  = (uint*)(csr_src + n_edges);

    int nwords = (n_nodes + 1) / 2;
    uint* partial_out = partial_in + (size_t)NCHUNK * nwords;

    size_t need = (size_t)((char*)(partial_out + (size_t)NCHUNK * nwords) - ws);
    int epb = (n_edges + NCHUNK - 1) / NCHUNK;
    bool fast = (nwords <= NNW_MAX) && (epb < 65536) && (need <= ws_size);

    if (fast) {
        int rwh = (nwords + NRH - 1) / NRH;
        hist_kernel<<<dim3(NCHUNK, 2, NRH), 512, 0, stream>>>(
            src, dst, partial_in, partial_out, n_edges, nwords, epb, rwh);
        degnormrel_kernel<<<(nwords + 255) / 256, 256, 0, stream>>>(
            partial_in, partial_out, deg_in, norm, nwords, n_nodes);
    } else {
        hipMemsetAsync(deg_in, 0, 2 * (size_t)n_nodes * sizeof(int), stream);
        deg_kernel<<<(n_edges + 255) / 256, 256, 0, stream>>>(src, dst, deg_out, deg_in, n_edges);
        norm_kernel<<<(n_nodes + 255) / 256, 256, 0, stream>>>(deg_out, deg_in, norm, n_nodes);
    }

    int total = n_nodes * 64;
    featn_kernel<<<(total + 255) / 256, 256, 0, stream>>>(feat, norm, featn, total);
    wt_kernel<<<(NF * NF / 2 + 255) / 256, 256, 0, stream>>>(W, wt);

    int nb = (n_nodes + 1023) / 1024;
    scan_sum_kernel<<<nb, 1024, 0, stream>>>(deg_in, bsum, n_nodes);
    scan_bsum_kernel<<<1, 1024, 0, stream>>>(bsum, nb);
    scan_final_kernel<<<nb, 1024, 0, stream>>>(deg_in, bsum, start, cursor, n_nodes);

    if (fast) {
        int rwf = (nwords + NRF - 1) / NRF;
        fill3_kernel<<<NCHUNK * NRF, 512, 0, stream>>>(src, dst, partial_out, start,
                                                       csr_src, n_edges, nwords, epb, rwf);
    } else {
        fill_kernel<<<(n_edges + 255) / 256, 256, 0, stream>>>(src, dst, cursor, csr_src, n_edges);
    }

    gather_kernel<<<(n_nodes * 64 + 255) / 256, 256, 0, stream>>>(featn, csr_src, start,
                                                                  deg_in, rst_h, n_nodes);
    gemm_mfma_kernel<<<(n_nodes + 63) / 64, 256, 0, stream>>>((const ushort*)rst_h,
                                                              (const ushort*)wt, bias,
                                                              (float*)d_out, n_nodes);
}